// Round 16
// baseline (6464.883 us; speedup 1.0000x reference)
//
#include <hip/hip_runtime.h>
#include <math.h>

// ---------------- problem constants ----------------
#define NBLK 128
#define NTHR 512      // 8 waves
#define NL0B 64       // blocks 0..63 -> layer0 (16 h-cols); 64..127 -> layer1 (16 h-cols)
#define BATCH 64
#define TT 512
#define INF 256
#define OUTF 256

typedef _Float16 f16;
typedef __attribute__((ext_vector_type(4))) _Float16 f16x4;
typedef __attribute__((ext_vector_type(8))) _Float16 f16x8;
typedef __attribute__((ext_vector_type(4))) float f32x4;
typedef __attribute__((ext_vector_type(4))) int i32x4;

// Workspace: S0[2], S1[2] rings ([64][1024] f16 = 128 KiB each), then flags.
// ALL S accesses are sc0+sc1 asm (L1/L2 bypass, L3-coherent) -> no fences.
#define SBUF_ELEMS 65536
#define S1_BASE (2 * SBUF_ELEMS)
#define FLAGS_OFF_BYTES ((size_t)4 * SBUF_ELEMS * 2)   // 512 KiB
#define WS_BYTES (FLAGS_OFF_BYTES + 1024)

// LDS (L0 layout): 128 KiB weights | 2 KiB h-stage | 16 KiB cross-wave reduce
#define HSTG_OFF 131072
#define RED_OFF  (131072 + 2048)
// LDS (L1 layout): partials 8w x 4q x 64 x 17 f32 = 139264 B | h-stage 2 KiB
#define L1_HSTG_OFF 139264
#define LDS_BYTES 153600

#define BARRIER_DEADLINE_TICKS 4000000ull   // 40 ms @100MHz; sticky bail

__device__ __forceinline__ float sig_(float v) { return 1.0f / (1.0f + __expf(-v)); }

#define GLOADX4(dst, p) \
  asm volatile("global_load_dwordx4 %0, %1, off sc0 sc1" : "=v"(dst) : "v"(p))
#define GLOADX4_C(dst, p) \
  asm volatile("global_load_dwordx4 %0, %1, off" : "=v"(dst) : "v"(p))
#define GSTOREX4(p, v_) \
  asm volatile("global_store_dwordx4 %0, %1, off sc0 sc1" :: "v"(p), "v"(v_) : "memory")
#define VWAIT(N) do { \
  asm volatile("s_waitcnt vmcnt(" #N ")" ::: "memory"); \
  __builtin_amdgcn_sched_barrier(0); } while (0)

#define MFMA(a, b, c) __builtin_amdgcn_mfma_f32_16x16x32_f16(a, b, c, 0, 0, 0)

__device__ __forceinline__ f16x8 cvt8(float4 u, float4 v) {
  f16x8 r;
  r[0]=(f16)u.x; r[1]=(f16)u.y; r[2]=(f16)u.z; r[3]=(f16)u.w;
  r[4]=(f16)v.x; r[5]=(f16)v.y; r[6]=(f16)v.z; r[7]=(f16)v.w;
  return r;
}

// Global barrier (proven r4-r14): all waves drain -> __syncthreads -> tid0
// publishes flags[b]=tgt (NC) -> wave 0 polls all 128 flags. Deadline-bail.
__device__ __forceinline__ void grid_barrier(int* flags, int tgt, bool& bail) {
  asm volatile("s_waitcnt vmcnt(0)" ::: "memory");
  __syncthreads();
  if (threadIdx.x == 0) {
    int* fp = flags + blockIdx.x;
    asm volatile("global_store_dword %0, %1, off sc0 sc1" :: "v"(fp), "v"(tgt) : "memory");
  }
  if (threadIdx.x < 64 && !bail) {
    const int* pp = flags + (threadIdx.x << 2);
    const unsigned long long t0 = __builtin_amdgcn_s_memrealtime();
    for (;;) {
      int ok = 1;
      if (threadIdx.x < 32) {
        i32x4 f4;
        asm volatile("global_load_dwordx4 %0, %1, off sc0 sc1\n\ts_waitcnt vmcnt(0)"
                     : "=v"(f4) : "v"(pp) : "memory");
        ok = (f4[0] >= tgt) & (f4[1] >= tgt) & (f4[2] >= tgt) & (f4[3] >= tgt);
      }
      if (__all(ok)) break;
      if (__builtin_amdgcn_s_memrealtime() - t0 > BARRIER_DEADLINE_TICKS) { bail = true; break; }
      __builtin_amdgcn_s_sleep(1);
    }
  }
  __syncthreads();
}

__global__ __launch_bounds__(NTHR, 1) void lstm_fused(
    const float* __restrict__ x,
    const float* __restrict__ w_ih_0, const float* __restrict__ w_hh_0,
    const float* __restrict__ b_ih_0, const float* __restrict__ b_hh_0,
    const float* __restrict__ w_ih_1, const float* __restrict__ w_hh_1,
    const float* __restrict__ b_ih_1, const float* __restrict__ b_hh_1,
    const float* __restrict__ w_fc, const float* __restrict__ b_fc,
    float* __restrict__ out, void* __restrict__ ws)
{
  extern __shared__ char smem[];
  f16* ws16 = (f16*)ws;
  int* flags = (int*)((char*)ws + FLAGS_OFF_BYTES);

  const int b = blockIdx.x;
  const int tid = threadIdx.x;
  const int wave = tid >> 6, lane = tid & 63;
  const int quad = wave & 3, kh = wave >> 2;
  const int col = lane & 15, krow = lane >> 4;
  const bool isL1 = (b >= NL0B);
  bool bail = false;

  // ---- zero the S rings (512 KiB) via NC stores ----
  {
    const int gt = b * NTHR + tid;
    if (gt < 32768) {
      i32x4 z = (i32x4){0, 0, 0, 0};
      char* p = (char*)ws + (size_t)gt * 16;
      GSTOREX4(p, z);
    }
  }

  if (!isL1) {
    // ============ LAYER 0: 64 blocks x 16 h-cols ============
    f16* wl = (f16*)smem;
    f16* hstg = (f16*)(smem + HSTG_OFF);
    float* red = (float*)(smem + RED_OFF);
    const int hc0 = b * 16;
    {   // stage w_hh_0 slice (K=1024, 64 gate-cols) -> wl [(k>>3)][64][8]
      const int c2 = tid >> 3, kpart = tid & 7;
      const int n = c2 >> 4, cc = c2 & 15;
      const int grow = n * 1024 + hc0 + cc;
      const float* src = w_hh_0 + (size_t)grow * 1024;
      for (int k = kpart * 128; k < kpart * 128 + 128; k += 4) {
        float4 v = *(const float4*)(src + k);
        f16x4 hv; hv[0]=(f16)v.x; hv[1]=(f16)v.y; hv[2]=(f16)v.z; hv[3]=(f16)v.w;
        *(f16x4*)&wl[((size_t)(k >> 3) * 64 + c2) * 8 + (k & 7)] = hv;
      }
    }
    f16x8 wx[16];
#pragma unroll
    for (int n = 0; n < 4; ++n)
#pragma unroll
      for (int kc2 = 0; kc2 < 4; ++kc2) {
        const int kc = kh * 4 + kc2;
        const float* p = w_ih_0 + (size_t)(n * 1024 + hc0 + col) * 256 + kc * 32 + krow * 8;
        wx[n * 4 + kc2] = cvt8(*(const float4*)p, *(const float4*)(p + 4));
      }
    const int gi = hc0 + col;
    const float bi  = b_ih_0[gi]        + b_hh_0[gi];
    const float bf_ = b_ih_0[1024 + gi] + b_hh_0[1024 + gi];
    const float bg  = b_ih_0[2048 + gi] + b_hh_0[2048 + gi];
    const float bo  = b_ih_0[3072 + gi] + b_hh_0[3072 + gi];
    float creg[4] = {0.f, 0.f, 0.f, 0.f};

    f32x4 accX0 = (f32x4){0,0,0,0}, accX1 = (f32x4){0,0,0,0};
    f32x4 accX2 = (f32x4){0,0,0,0}, accX3 = (f32x4){0,0,0,0};
    {
      const float* xb0 = x + (size_t)(16 * quad + col) * TT * INF + krow * 8;
#pragma unroll
      for (int kc2 = 0; kc2 < 4; ++kc2) {
        const int kc = kh * 4 + kc2;
        f16x8 ax = cvt8(*(const float4*)(xb0 + kc * 32), *(const float4*)(xb0 + kc * 32 + 4));
        accX0 = MFMA(ax, wx[0 * 4 + kc2], accX0);
        accX1 = MFMA(ax, wx[1 * 4 + kc2], accX1);
        accX2 = MFMA(ax, wx[2 * 4 + kc2], accX2);
        accX3 = MFMA(ax, wx[3 * 4 + kc2], accX3);
      }
    }
    grid_barrier(flags, 1, bail);

    const f16* WbL0 = wl + krow * 512 + col * 8;
    const int cb = kh * 16;
    for (int r = 0; r <= TT; ++r) {
      if (r < TT) {
        f32x4 acc0 = accX0, acc1 = accX1, acc2 = accX2, acc3 = accX3;
        const f16* s0in = ws16 + (size_t)((r + 1) & 1) * SBUF_ELEMS;
        f16*       s0out = ws16 + (size_t)(r & 1) * SBUF_ELEMS;
        // ---- s0 phase FIRST (critical path): 16 chunks, all issued up front ----
        {
          i32x4 av[16];
          const f16* Ab = s0in + (size_t)(16 * quad + col) * 1024 + krow * 8;
#pragma unroll
          for (int i = 0; i < 16; ++i) { const f16* p = Ab + (cb + i) * 32; GLOADX4(av[i], p); }
#define L0CONS4(SLOT0) do { _Pragma("unroll") for (int q_ = 0; q_ < 4; ++q_) { \
    f16x8 a_ = __builtin_bit_cast(f16x8, av[(SLOT0) + q_]); \
    const f16* wp_ = WbL0 + (size_t)(cb + (SLOT0) + q_) * 2048; \
    f16x8 w0_ = *(const f16x8*)(wp_); \
    f16x8 w1_ = *(const f16x8*)(wp_ + 128); \
    f16x8 w2_ = *(const f16x8*)(wp_ + 256); \
    f16x8 w3_ = *(const f16x8*)(wp_ + 384); \
    acc0 = MFMA(a_, w0_, acc0); acc1 = MFMA(a_, w1_, acc1); \
    acc2 = MFMA(a_, w2_, acc2); acc3 = MFMA(a_, w3_, acc3); } } while (0)
          VWAIT(12); L0CONS4(0);
          VWAIT(8);  L0CONS4(4);
          VWAIT(4);  L0CONS4(8);
          VWAIT(0);  L0CONS4(12);
#undef L0CONS4
        }
        // ---- cross-wave K-half combine + epilogue ----
        if (kh == 1) {
          float* rp = red + (size_t)quad * 1024 + (size_t)lane * 16;
          *(f32x4*)(rp + 0)  = acc0;
          *(f32x4*)(rp + 4)  = acc1;
          *(f32x4*)(rp + 8)  = acc2;
          *(f32x4*)(rp + 12) = acc3;
        }
        __syncthreads();
        if (kh == 0) {
          const float* rp = red + (size_t)quad * 1024 + (size_t)lane * 16;
          acc0 += *(const f32x4*)(rp + 0);
          acc1 += *(const f32x4*)(rp + 4);
          acc2 += *(const f32x4*)(rp + 8);
          acc3 += *(const f32x4*)(rp + 12);
#pragma unroll
          for (int j = 0; j < 4; ++j) {
            float iv = acc0[j] + bi, fv = acc1[j] + bf_;
            float gv = acc2[j] + bg, ov = acc3[j] + bo;
            float cn = sig_(fv) * creg[j] + sig_(iv) * tanhf(gv);
            float hn = sig_(ov) * tanhf(cn);
            creg[j] = cn;
            hstg[(16 * quad + krow * 4 + j) * 16 + col] = (f16)hn;
          }
        }
        __syncthreads();
        if (tid < 64) {   // publish h (drained by the barrier's vmcnt(0))
          i32x4 v0 = *(const i32x4*)&hstg[tid * 16];
          i32x4 v1 = *(const i32x4*)&hstg[tid * 16 + 8];
          f16* p = s0out + (size_t)tid * 1024 + hc0;
          GSTOREX4(p, v0);
          f16* p2 = p + 8;
          GSTOREX4(p2, v1);
        }
        // ---- x phase for t=r+1 AFTER publish: overlaps barrier propagation ----
        {
          const bool dox = (r + 1) < TT;
          const float* xb = x + (size_t)(16 * quad + col) * TT * INF
                              + (size_t)(dox ? r + 1 : r) * INF + krow * 8;
          accX0 = (f32x4){0,0,0,0}; accX1 = (f32x4){0,0,0,0};
          accX2 = (f32x4){0,0,0,0}; accX3 = (f32x4){0,0,0,0};
          i32x4 xv[8];
#pragma unroll
          for (int i = 0; i < 8; ++i) {
            const float* p_ = xb + (kh * 4 + (i >> 1)) * 32 + (i & 1) * 4;
            GLOADX4_C(xv[i], p_);
          }
          VWAIT(0);
#pragma unroll
          for (int q = 0; q < 4; ++q) {
            f16x8 ax_ = cvt8(__builtin_bit_cast(float4, xv[2 * q]),
                             __builtin_bit_cast(float4, xv[2 * q + 1]));
            accX0 = MFMA(ax_, wx[0 * 4 + q], accX0);
            accX1 = MFMA(ax_, wx[1 * 4 + q], accX1);
            accX2 = MFMA(ax_, wx[2 * 4 + q], accX2);
            accX3 = MFMA(ax_, wx[3 * 4 + q], accX3);
          }
        }
      }
      grid_barrier(flags, r + 2, bail);
    }
  } else {
    // ===== LAYER 1: 64 blocks x 16 h-cols; VGPR weights, quad-pipelined =====
    float* pl1 = (float*)smem;                  // partials ((w*4+QQ)*64+lane)*17
    f16* hstg1 = (f16*)(smem + L1_HSTG_OFF);
    const int bb = b - NL0B;
    const int hc0 = bb * 16;
    const int kslice = wave & 3;
    const bool useS1 = (wave >= 4);
    f16x8 w1r[32];
    {
      const float* wsrc = useS1 ? w_hh_1 : w_ih_1;
#pragma unroll
      for (int n = 0; n < 4; ++n)
#pragma unroll
        for (int kc = 0; kc < 8; ++kc) {
          const float* p = wsrc + (size_t)(n * 1024 + hc0 + col) * 1024
                           + kslice * 256 + kc * 32 + krow * 8;
          w1r[n * 8 + kc] = cvt8(*(const float4*)p, *(const float4*)(p + 4));
        }
    }
    float bce[4], creg2[2] = {0.f, 0.f};
    {
      const int c = tid & 15;
#pragma unroll
      for (int n = 0; n < 4; ++n)
        bce[n] = b_ih_1[n * 1024 + hc0 + c] + b_hh_1[n * 1024 + hc0 + c];
    }
    grid_barrier(flags, 1, bail);

    for (int r = 0; r <= TT; ++r) {
      if (r >= 1) {
        const f16* s0in = ws16 + (size_t)((r + 1) & 1) * SBUF_ELEMS;             // s0[r-1]
        const f16* s1in = ws16 + S1_BASE + (size_t)(r & 1) * SBUF_ELEMS;         // s1[r-2]
        f16*       s1out = ws16 + S1_BASE + (size_t)((r + 1) & 1) * SBUF_ELEMS;  // s1[r-1]
        const f16* Asrc = useS1 ? s1in : s0in;
        // ---- 4 batch-quads, 2-deep software pipeline (bv0/bv1, VWAIT(8)) ----
        i32x4 bv0[8], bv1[8];
#define ISSQ(BV, QQ) do { \
    const f16* Abq_ = Asrc + (size_t)(16 * (QQ) + col) * 1024 + kslice * 256 + krow * 8; \
    _Pragma("unroll") for (int i_ = 0; i_ < 8; ++i_) { \
      const f16* p_ = Abq_ + i_ * 32; GLOADX4(BV[i_], p_); } } while (0)
#define CONSQ(BV, QQ) do { \
    f32x4 a0 = (f32x4){0,0,0,0}, a1 = (f32x4){0,0,0,0}; \
    f32x4 a2 = (f32x4){0,0,0,0}, a3 = (f32x4){0,0,0,0}; \
    _Pragma("unroll") for (int kc_ = 0; kc_ < 8; ++kc_) { \
      f16x8 a_ = __builtin_bit_cast(f16x8, BV[kc_]); \
      a0 = MFMA(a_, w1r[0 * 8 + kc_], a0); a1 = MFMA(a_, w1r[1 * 8 + kc_], a1); \
      a2 = MFMA(a_, w1r[2 * 8 + kc_], a2); a3 = MFMA(a_, w1r[3 * 8 + kc_], a3); } \
    float* pb_ = pl1 + ((size_t)(wave * 4 + (QQ)) * 64 + lane) * 17; \
    *(f32x4*)(pb_ + 0)  = a0; \
    *(f32x4*)(pb_ + 4)  = a1; \
    *(f32x4*)(pb_ + 8)  = a2; \
    *(f32x4*)(pb_ + 12) = a3; } while (0)
        ISSQ(bv0, 0); ISSQ(bv1, 1);
        VWAIT(8); CONSQ(bv0, 0); ISSQ(bv0, 2);
        VWAIT(8); CONSQ(bv1, 1); ISSQ(bv1, 3);
        VWAIT(8); CONSQ(bv0, 2);
        VWAIT(0); CONSQ(bv1, 3);
#undef ISSQ
#undef CONSQ
        __syncthreads();
        // ---- reduce 8 wave-partials + LSTM epilogue: 512 thr x 2 cells ----
#pragma unroll
        for (int s2 = 0; s2 < 2; ++s2) {
          const int cell = tid + s2 * 512;          // row*16 + c
          const int row = cell >> 4, c = cell & 15;
          const int QQ = row >> 4, l4 = (row >> 2) & 3, j = row & 3;
          const int ln = l4 * 16 + c;
          float g4[4];
#pragma unroll
          for (int n = 0; n < 4; ++n) {
            float s = 0.f;
#pragma unroll
            for (int w = 0; w < 8; ++w)
              s += pl1[((size_t)(w * 4 + QQ) * 64 + ln) * 17 + n * 4 + j];
            g4[n] = s;
          }
          float iv = g4[0] + bce[0], fv = g4[1] + bce[1];
          float gv = g4[2] + bce[2], ov = g4[3] + bce[3];
          float cn = sig_(fv) * creg2[s2] + sig_(iv) * tanhf(gv);
          float hn = sig_(ov) * tanhf(cn);
          creg2[s2] = cn;
          hstg1[cell] = (f16)hn;
        }
        __syncthreads();
        if (tid < 64) {
          i32x4 v0 = *(const i32x4*)&hstg1[tid * 16];
          i32x4 v1 = *(const i32x4*)&hstg1[tid * 16 + 8];
          f16* p = s1out + (size_t)tid * 1024 + hc0;
          GSTOREX4(p, v0);
          f16* p2 = p + 8;
          GSTOREX4(p2, v1);
        }
      }
      grid_barrier(flags, r + 2, bail);
    }
  }

  // ---- FC on last timestep: cols c = b, b+128 ----
  {
    float* redf = (float*)smem;   // weights/partials dead
    const f16* Afc = ws16 + S1_BASE + (size_t)1 * SBUF_ELEMS;   // s1[511] parity 1
    const int row = tid & 63, kq = tid >> 6;
    for (int c = b; c < OUTF; c += NBLK) {
      const f16* ph = Afc + (size_t)row * 1024 + kq * 128;
      const float* pw = w_fc + (size_t)c * 1024 + kq * 128;
      float acc = 0.f;
#pragma unroll 4
      for (int k = 0; k < 128; ++k)
        acc = fmaf((float)ph[k], pw[k], acc);
      __syncthreads();
      redf[tid] = acc;
      __syncthreads();
      if (tid < 64) {
        float s = b_fc[c];
#pragma unroll
        for (int q = 0; q < 8; ++q) s += redf[tid + 64 * q];
        out[(size_t)tid * OUTF + c] = s;
      }
    }
  }
}

extern "C" void kernel_launch(void* const* d_in, const int* in_sizes, int n_in,
                              void* d_out, int out_size, void* d_ws, size_t ws_size,
                              hipStream_t stream) {
  const float* x      = (const float*)d_in[0];
  const float* w_ih_0 = (const float*)d_in[1];
  const float* w_hh_0 = (const float*)d_in[2];
  const float* b_ih_0 = (const float*)d_in[3];
  const float* b_hh_0 = (const float*)d_in[4];
  const float* w_ih_1 = (const float*)d_in[5];
  const float* w_hh_1 = (const float*)d_in[6];
  const float* b_ih_1 = (const float*)d_in[7];
  const float* b_hh_1 = (const float*)d_in[8];
  const float* w_fc   = (const float*)d_in[9];
  const float* b_fc   = (const float*)d_in[10];
  float* out = (float*)d_out;
  void* ws = d_ws;

  if (ws_size < WS_BYTES) return;   // clean failure signature, no VM fault

  hipMemsetAsync((char*)d_ws + FLAGS_OFF_BYTES, 0, 1024, stream);
  hipFuncSetAttribute((const void*)lstm_fused,
                      hipFuncAttributeMaxDynamicSharedMemorySize, LDS_BYTES);

  void* args[] = {
    (void*)&x, (void*)&w_ih_0, (void*)&w_hh_0, (void*)&b_ih_0, (void*)&b_hh_0,
    (void*)&w_ih_1, (void*)&w_hh_1, (void*)&b_ih_1, (void*)&b_hh_1,
    (void*)&w_fc, (void*)&b_fc, (void*)&out, (void*)&ws
  };
  hipError_t err = hipLaunchCooperativeKernel((void*)lstm_fused, dim3(NBLK), dim3(NTHR),
                                              args, LDS_BYTES, stream);
  if (err != hipSuccess) {
    (void)hipGetLastError();
    lstm_fused<<<dim3(NBLK), dim3(NTHR), LDS_BYTES, stream>>>(
        x, w_ih_0, w_hh_0, b_ih_0, b_hh_0, w_ih_1, w_hh_1, b_ih_1, b_hh_1,
        w_fc, b_fc, out, ws);
  }
}

// Round 18
// 6282.957 us; speedup vs baseline: 1.0290x; 1.0290x over previous
//
#include <hip/hip_runtime.h>
#include <math.h>

// ---------------- problem constants ----------------
#define NBLK 128
#define NTHR 512      // 8 waves
#define NL0B 64       // blocks 0..63 -> layer0 (16 h-cols); 64..127 -> layer1 (16 h-cols)
#define BATCH 64
#define TT 512
#define INF 256
#define OUTF 256

typedef _Float16 f16;
typedef __attribute__((ext_vector_type(4))) _Float16 f16x4;
typedef __attribute__((ext_vector_type(8))) _Float16 f16x8;
typedef __attribute__((ext_vector_type(4))) float f32x4;
typedef __attribute__((ext_vector_type(4))) int i32x4;

// Workspace: S0[2], S1[2] rings ([64][1024] f16 = 128 KiB each), then flags.
// ALL S accesses are sc0+sc1 asm (L1/L2 bypass, L3-coherent) -> no fences.
#define SBUF_ELEMS 65536
#define S1_BASE (2 * SBUF_ELEMS)
#define FLAGS_OFF_BYTES ((size_t)4 * SBUF_ELEMS * 2)   // 512 KiB
#define WS_BYTES (FLAGS_OFF_BYTES + 1024)

// LDS (L0 layout): 128 KiB weights | 2 KiB h-stage | 16 KiB cross-wave reduce
#define HSTG_OFF 131072
#define RED_OFF  (131072 + 2048)
// LDS (L1 layout): partials 8w x 4q x 64 x 17 f32 = 139264 B | h-stage 2 KiB
#define L1_HSTG_OFF 139264
#define LDS_BYTES 153600

#define BARRIER_DEADLINE_TICKS 4000000ull   // 40 ms @100MHz; sticky bail

__device__ __forceinline__ float sig_(float v) { return 1.0f / (1.0f + __expf(-v)); }

#define GLOADX4(dst, p) \
  asm volatile("global_load_dwordx4 %0, %1, off sc0 sc1" : "=v"(dst) : "v"(p))
#define GLOADX4_C(dst, p) \
  asm volatile("global_load_dwordx4 %0, %1, off" : "=v"(dst) : "v"(p))
#define GSTOREX4(p, v_) \
  asm volatile("global_store_dwordx4 %0, %1, off sc0 sc1" :: "v"(p), "v"(v_) : "memory")
#define VWAIT(N) do { \
  asm volatile("s_waitcnt vmcnt(" #N ")" ::: "memory"); \
  __builtin_amdgcn_sched_barrier(0); } while (0)

#define MFMA(a, b, c) __builtin_amdgcn_mfma_f32_16x16x32_f16(a, b, c, 0, 0, 0)

__device__ __forceinline__ f16x8 cvt8(float4 u, float4 v) {
  f16x8 r;
  r[0]=(f16)u.x; r[1]=(f16)u.y; r[2]=(f16)u.z; r[3]=(f16)u.w;
  r[4]=(f16)v.x; r[5]=(f16)v.y; r[6]=(f16)v.z; r[7]=(f16)v.w;
  return r;
}

// Global barrier (proven r4-r16): all waves drain -> __syncthreads -> tid0
// publishes flags[b]=tgt (NC) -> wave 0 polls all 128 flags. Deadline-bail.
__device__ __forceinline__ void grid_barrier(int* flags, int tgt, bool& bail) {
  asm volatile("s_waitcnt vmcnt(0)" ::: "memory");
  __syncthreads();
  if (threadIdx.x == 0) {
    int* fp = flags + blockIdx.x;
    asm volatile("global_store_dword %0, %1, off sc0 sc1" :: "v"(fp), "v"(tgt) : "memory");
  }
  if (threadIdx.x < 64 && !bail) {
    const int* pp = flags + (threadIdx.x << 2);
    const unsigned long long t0 = __builtin_amdgcn_s_memrealtime();
    for (;;) {
      int ok = 1;
      if (threadIdx.x < 32) {
        i32x4 f4;
        asm volatile("global_load_dwordx4 %0, %1, off sc0 sc1\n\ts_waitcnt vmcnt(0)"
                     : "=v"(f4) : "v"(pp) : "memory");
        ok = (f4[0] >= tgt) & (f4[1] >= tgt) & (f4[2] >= tgt) & (f4[3] >= tgt);
      }
      if (__all(ok)) break;
      if (__builtin_amdgcn_s_memrealtime() - t0 > BARRIER_DEADLINE_TICKS) { bail = true; break; }
      __builtin_amdgcn_s_sleep(1);
    }
  }
  __syncthreads();
}

__global__ __launch_bounds__(NTHR, 1) void lstm_fused(
    const float* __restrict__ x,
    const float* __restrict__ w_ih_0, const float* __restrict__ w_hh_0,
    const float* __restrict__ b_ih_0, const float* __restrict__ b_hh_0,
    const float* __restrict__ w_ih_1, const float* __restrict__ w_hh_1,
    const float* __restrict__ b_ih_1, const float* __restrict__ b_hh_1,
    const float* __restrict__ w_fc, const float* __restrict__ b_fc,
    float* __restrict__ out, void* __restrict__ ws)
{
  extern __shared__ char smem[];
  f16* ws16 = (f16*)ws;
  int* flags = (int*)((char*)ws + FLAGS_OFF_BYTES);

  const int b = blockIdx.x;
  const int tid = threadIdx.x;
  const int wave = tid >> 6, lane = tid & 63;
  const int quad = wave & 3, kh = wave >> 2;
  const int col = lane & 15, krow = lane >> 4;
  const bool isL1 = (b >= NL0B);
  bool bail = false;

  // ---- zero the S rings (512 KiB) via NC stores ----
  {
    const int gt = b * NTHR + tid;
    if (gt < 32768) {
      i32x4 z = (i32x4){0, 0, 0, 0};
      char* p = (char*)ws + (size_t)gt * 16;
      GSTOREX4(p, z);
    }
  }

  if (!isL1) {
    // ============ LAYER 0: 64 blocks x 16 h-cols ============
    f16* wl = (f16*)smem;
    f16* hstg = (f16*)(smem + HSTG_OFF);
    float* red = (float*)(smem + RED_OFF);
    const int hc0 = b * 16;
    {   // stage w_hh_0 slice (K=1024, 64 gate-cols) -> wl [(k>>3)][64][8]
      const int c2 = tid >> 3, kpart = tid & 7;
      const int n = c2 >> 4, cc = c2 & 15;
      const int grow = n * 1024 + hc0 + cc;
      const float* src = w_hh_0 + (size_t)grow * 1024;
      for (int k = kpart * 128; k < kpart * 128 + 128; k += 4) {
        float4 v = *(const float4*)(src + k);
        f16x4 hv; hv[0]=(f16)v.x; hv[1]=(f16)v.y; hv[2]=(f16)v.z; hv[3]=(f16)v.w;
        *(f16x4*)&wl[((size_t)(k >> 3) * 64 + c2) * 8 + (k & 7)] = hv;
      }
    }
    f16x8 wx[16];
#pragma unroll
    for (int n = 0; n < 4; ++n)
#pragma unroll
      for (int kc2 = 0; kc2 < 4; ++kc2) {
        const int kc = kh * 4 + kc2;
        const float* p = w_ih_0 + (size_t)(n * 1024 + hc0 + col) * 256 + kc * 32 + krow * 8;
        wx[n * 4 + kc2] = cvt8(*(const float4*)p, *(const float4*)(p + 4));
      }
    const int gi = hc0 + col;
    const float bi  = b_ih_0[gi]        + b_hh_0[gi];
    const float bf_ = b_ih_0[1024 + gi] + b_hh_0[1024 + gi];
    const float bg  = b_ih_0[2048 + gi] + b_hh_0[2048 + gi];
    const float bo  = b_ih_0[3072 + gi] + b_hh_0[3072 + gi];
    float creg[4] = {0.f, 0.f, 0.f, 0.f};

    f32x4 accX0 = (f32x4){0,0,0,0}, accX1 = (f32x4){0,0,0,0};
    f32x4 accX2 = (f32x4){0,0,0,0}, accX3 = (f32x4){0,0,0,0};
    {
      const float* xb0 = x + (size_t)(16 * quad + col) * TT * INF + krow * 8;
#pragma unroll
      for (int kc2 = 0; kc2 < 4; ++kc2) {
        const int kc = kh * 4 + kc2;
        f16x8 ax = cvt8(*(const float4*)(xb0 + kc * 32), *(const float4*)(xb0 + kc * 32 + 4));
        accX0 = MFMA(ax, wx[0 * 4 + kc2], accX0);
        accX1 = MFMA(ax, wx[1 * 4 + kc2], accX1);
        accX2 = MFMA(ax, wx[2 * 4 + kc2], accX2);
        accX3 = MFMA(ax, wx[3 * 4 + kc2], accX3);
      }
    }
    grid_barrier(flags, 1, bail);

    const f16* WbL0 = wl + krow * 512 + col * 8;
    const int cb = kh * 16;
    for (int r = 0; r <= TT; ++r) {
      if (r < TT) {
        f32x4 acc0 = accX0, acc1 = accX1, acc2 = accX2, acc3 = accX3;
        const f16* s0in = ws16 + (size_t)((r + 1) & 1) * SBUF_ELEMS;
        f16*       s0out = ws16 + (size_t)(r & 1) * SBUF_ELEMS;
        const bool dox = (r + 1) < TT;
        const float* xb = x + (size_t)(16 * quad + col) * TT * INF
                            + (size_t)(dox ? r + 1 : r) * INF + krow * 8;
        accX0 = (f32x4){0,0,0,0}; accX1 = (f32x4){0,0,0,0};
        accX2 = (f32x4){0,0,0,0}; accX3 = (f32x4){0,0,0,0};
        {
          i32x4 xv[8];
#pragma unroll
          for (int i = 0; i < 8; ++i) {
            const float* p_ = xb + (kh * 4 + (i >> 1)) * 32 + (i & 1) * 4;
            GLOADX4_C(xv[i], p_);
          }
          VWAIT(0);
#pragma unroll
          for (int q = 0; q < 4; ++q) {
            f16x8 ax_ = cvt8(__builtin_bit_cast(float4, xv[2 * q]),
                             __builtin_bit_cast(float4, xv[2 * q + 1]));
            accX0 = MFMA(ax_, wx[0 * 4 + q], accX0);
            accX1 = MFMA(ax_, wx[1 * 4 + q], accX1);
            accX2 = MFMA(ax_, wx[2 * 4 + q], accX2);
            accX3 = MFMA(ax_, wx[3 * 4 + q], accX3);
          }
        }
        {
          i32x4 av[8];
          const f16* Ab = s0in + (size_t)(16 * quad + col) * 1024 + krow * 8;
#pragma unroll
          for (int i = 0; i < 8; ++i) { const f16* p = Ab + (cb + i) * 32; GLOADX4(av[i], p); }
#define L0CONS4(SLOT0, C0) do { _Pragma("unroll") for (int q_ = 0; q_ < 4; ++q_) { \
    f16x8 a_ = __builtin_bit_cast(f16x8, av[(SLOT0) + q_]); \
    const f16* wp_ = WbL0 + (size_t)(cb + (C0) + q_) * 2048; \
    f16x8 w0_ = *(const f16x8*)(wp_); \
    f16x8 w1_ = *(const f16x8*)(wp_ + 128); \
    f16x8 w2_ = *(const f16x8*)(wp_ + 256); \
    f16x8 w3_ = *(const f16x8*)(wp_ + 384); \
    acc0 = MFMA(a_, w0_, acc0); acc1 = MFMA(a_, w1_, acc1); \
    acc2 = MFMA(a_, w2_, acc2); acc3 = MFMA(a_, w3_, acc3); } } while (0)
#define L0ISS4(SLOT0, C0) do { _Pragma("unroll") for (int q_ = 0; q_ < 4; ++q_) { \
    const f16* p_ = Ab + (size_t)(cb + (C0) + q_) * 32; \
    GLOADX4(av[(SLOT0) + q_], p_); } } while (0)
          VWAIT(4); L0CONS4(0, 0);  L0ISS4(0, 8);
          VWAIT(4); L0CONS4(4, 4);  L0ISS4(4, 12);
          VWAIT(4); L0CONS4(0, 8);
          VWAIT(0); L0CONS4(4, 12);
#undef L0CONS4
#undef L0ISS4
        }
        if (kh == 1) {
          float* rp = red + (size_t)quad * 1024 + (size_t)lane * 16;
          *(f32x4*)(rp + 0)  = acc0;
          *(f32x4*)(rp + 4)  = acc1;
          *(f32x4*)(rp + 8)  = acc2;
          *(f32x4*)(rp + 12) = acc3;
        }
        __syncthreads();
        if (kh == 0) {
          const float* rp = red + (size_t)quad * 1024 + (size_t)lane * 16;
          acc0 += *(const f32x4*)(rp + 0);
          acc1 += *(const f32x4*)(rp + 4);
          acc2 += *(const f32x4*)(rp + 8);
          acc3 += *(const f32x4*)(rp + 12);
#pragma unroll
          for (int j = 0; j < 4; ++j) {
            float iv = acc0[j] + bi, fv = acc1[j] + bf_;
            float gv = acc2[j] + bg, ov = acc3[j] + bo;
            float cn = sig_(fv) * creg[j] + sig_(iv) * tanhf(gv);
            float hn = sig_(ov) * tanhf(cn);
            creg[j] = cn;
            hstg[(16 * quad + krow * 4 + j) * 16 + col] = (f16)hn;
          }
        }
        __syncthreads();
        if (tid < 64) {
          i32x4 v0 = *(const i32x4*)&hstg[tid * 16];
          i32x4 v1 = *(const i32x4*)&hstg[tid * 16 + 8];
          f16* p = s0out + (size_t)tid * 1024 + hc0;
          GSTOREX4(p, v0);
          f16* p2 = p + 8;
          GSTOREX4(p2, v1);
        }
      }
      grid_barrier(flags, r + 2, bail);
    }
  } else {
    // ===== LAYER 1: 64 blocks x 16 h-cols; ALL weights in VGPRs, LDS reduce =====
    float* pl1 = (float*)smem;                  // partials ((w*4+QQ)*64+lane)*17
    f16* hstg1 = (f16*)(smem + L1_HSTG_OFF);
    const int bb = b - NL0B;
    const int hc0 = bb * 16;
    const int kslice = wave & 3;
    const bool useS1 = (wave >= 4);
    f16x8 w1r[32];
    {
      const float* wsrc = useS1 ? w_hh_1 : w_ih_1;
#pragma unroll
      for (int n = 0; n < 4; ++n)
#pragma unroll
        for (int kc = 0; kc < 8; ++kc) {
          const float* p = wsrc + (size_t)(n * 1024 + hc0 + col) * 1024
                           + kslice * 256 + kc * 32 + krow * 8;
          w1r[n * 8 + kc] = cvt8(*(const float4*)p, *(const float4*)(p + 4));
        }
    }
    float bce[4], creg2[2] = {0.f, 0.f};
    {
      const int c = tid & 15;
#pragma unroll
      for (int n = 0; n < 4; ++n)
        bce[n] = b_ih_1[n * 1024 + hc0 + c] + b_hh_1[n * 1024 + hc0 + c];
    }
    grid_barrier(flags, 1, bail);

    for (int r = 0; r <= TT; ++r) {
      if (r >= 1) {
        const f16* s0in = ws16 + (size_t)((r + 1) & 1) * SBUF_ELEMS;             // s0[r-1]
        const f16* s1in = ws16 + S1_BASE + (size_t)(r & 1) * SBUF_ELEMS;         // s1[r-2]
        f16*       s1out = ws16 + S1_BASE + (size_t)((r + 1) & 1) * SBUF_ELEMS;  // s1[r-1]
        const f16* Asrc = useS1 ? s1in : s0in;
#pragma unroll
        for (int QQ = 0; QQ < 4; ++QQ) {
          const f16* Abq = Asrc + (size_t)(16 * QQ + col) * 1024 + kslice * 256 + krow * 8;
          i32x4 bv[8];
#pragma unroll
          for (int i = 0; i < 8; ++i) { const f16* p_ = Abq + i * 32; GLOADX4(bv[i], p_); }
          f32x4 a0 = (f32x4){0,0,0,0}, a1 = (f32x4){0,0,0,0};
          f32x4 a2 = (f32x4){0,0,0,0}, a3 = (f32x4){0,0,0,0};
          VWAIT(4);
#pragma unroll
          for (int kc = 0; kc < 4; ++kc) {
            f16x8 a_ = __builtin_bit_cast(f16x8, bv[kc]);
            a0 = MFMA(a_, w1r[0 * 8 + kc], a0); a1 = MFMA(a_, w1r[1 * 8 + kc], a1);
            a2 = MFMA(a_, w1r[2 * 8 + kc], a2); a3 = MFMA(a_, w1r[3 * 8 + kc], a3);
          }
          VWAIT(0);
#pragma unroll
          for (int kc = 4; kc < 8; ++kc) {
            f16x8 a_ = __builtin_bit_cast(f16x8, bv[kc]);
            a0 = MFMA(a_, w1r[0 * 8 + kc], a0); a1 = MFMA(a_, w1r[1 * 8 + kc], a1);
            a2 = MFMA(a_, w1r[2 * 8 + kc], a2); a3 = MFMA(a_, w1r[3 * 8 + kc], a3);
          }
          float* pb = pl1 + ((size_t)(wave * 4 + QQ) * 64 + lane) * 17;
          *(f32x4*)(pb + 0)  = a0;
          *(f32x4*)(pb + 4)  = a1;
          *(f32x4*)(pb + 8)  = a2;
          *(f32x4*)(pb + 12) = a3;
        }
        __syncthreads();
#pragma unroll
        for (int s2 = 0; s2 < 2; ++s2) {
          const int cell = tid + s2 * 512;          // row*16 + c
          const int row = cell >> 4, c = cell & 15;
          const int QQ = row >> 4, l4 = (row >> 2) & 3, j = row & 3;
          const int ln = l4 * 16 + c;
          float g4[4];
#pragma unroll
          for (int n = 0; n < 4; ++n) {
            float s = 0.f;
#pragma unroll
            for (int w = 0; w < 8; ++w)
              s += pl1[((size_t)(w * 4 + QQ) * 64 + ln) * 17 + n * 4 + j];
            g4[n] = s;
          }
          float iv = g4[0] + bce[0], fv = g4[1] + bce[1];
          float gv = g4[2] + bce[2], ov = g4[3] + bce[3];
          float cn = sig_(fv) * creg2[s2] + sig_(iv) * tanhf(gv);
          float hn = sig_(ov) * tanhf(cn);
          creg2[s2] = cn;
          hstg1[cell] = (f16)hn;
        }
        __syncthreads();
        if (tid < 64) {
          i32x4 v0 = *(const i32x4*)&hstg1[tid * 16];
          i32x4 v1 = *(const i32x4*)&hstg1[tid * 16 + 8];
          f16* p = s1out + (size_t)tid * 1024 + hc0;
          GSTOREX4(p, v0);
          f16* p2 = p + 8;
          GSTOREX4(p2, v1);
        }
      }
      grid_barrier(flags, r + 2, bail);
    }
  }

  // ---- FC on last timestep: cols c = b, b+128 ----
  {
    float* redf = (float*)smem;   // weights/partials dead
    const f16* Afc = ws16 + S1_BASE + (size_t)1 * SBUF_ELEMS;   // s1[511] parity 1
    const int row = tid & 63, kq = tid >> 6;
    for (int c = b; c < OUTF; c += NBLK) {
      const f16* ph = Afc + (size_t)row * 1024 + kq * 128;
      const float* pw = w_fc + (size_t)c * 1024 + kq * 128;
      float acc = 0.f;
#pragma unroll 4
      for (int k = 0; k < 128; ++k)
        acc = fmaf((float)ph[k], pw[k], acc);
      __syncthreads();
      redf[tid] = acc;
      __syncthreads();
      if (tid < 64) {
        float s = b_fc[c];
#pragma unroll
        for (int q = 0; q < 8; ++q) s += redf[tid + 64 * q];
        out[(size_t)tid * OUTF + c] = s;
      }
    }
  }
}

extern "C" void kernel_launch(void* const* d_in, const int* in_sizes, int n_in,
                              void* d_out, int out_size, void* d_ws, size_t ws_size,
                              hipStream_t stream) {
  const float* x      = (const float*)d_in[0];
  const float* w_ih_0 = (const float*)d_in[1];
  const float* w_hh_0 = (const float*)d_in[2];
  const float* b_ih_0 = (const float*)d_in[3];
  const float* b_hh_0 = (const float*)d_in[4];
  const float* w_ih_1 = (const float*)d_in[5];
  const float* w_hh_1 = (const float*)d_in[6];
  const float* b_ih_1 = (const float*)d_in[7];
  const float* b_hh_1 = (const float*)d_in[8];
  const float* w_fc   = (const float*)d_in[9];
  const float* b_fc   = (const float*)d_in[10];
  float* out = (float*)d_out;
  void* ws = d_ws;

  if (ws_size < WS_BYTES) return;   // clean failure signature, no VM fault

  hipMemsetAsync((char*)d_ws + FLAGS_OFF_BYTES, 0, 1024, stream);
  hipFuncSetAttribute((const void*)lstm_fused,
                      hipFuncAttributeMaxDynamicSharedMemorySize, LDS_BYTES);

  void* args[] = {
    (void*)&x, (void*)&w_ih_0, (void*)&w_hh_0, (void*)&b_ih_0, (void*)&b_hh_0,
    (void*)&w_ih_1, (void*)&w_hh_1, (void*)&b_ih_1, (void*)&b_hh_1,
    (void*)&w_fc, (void*)&b_fc, (void*)&out, (void*)&ws
  };
  hipError_t err = hipLaunchCooperativeKernel((void*)lstm_fused, dim3(NBLK), dim3(NTHR),
                                              args, LDS_BYTES, stream);
  if (err != hipSuccess) {
    (void)hipGetLastError();
    lstm_fused<<<dim3(NBLK), dim3(NTHR), LDS_BYTES, stream>>>(
        x, w_ih_0, w_hh_0, b_ih_0, b_hh_0, w_ih_1, w_hh_1, b_ih_1, b_hh_1,
        w_fc, b_fc, out, ws);
  }
}